// Round 3
// baseline (1419.434 us; speedup 1.0000x reference)
//
#include <hip/hip_runtime.h>
#include <cstdint>
#include <cstddef>

#define NN 8192
#define ATOMF 64
#define HID 128
#define HEADS 8
#define NG 256
#define ELLW 192
#define NEGSLOPE 0.2f
#define NB 1024            // blocks; 4/CU x 256 CUs, guaranteed co-resident via launch_bounds

// ---- grid-wide barrier: monotonic counter, agent scope, L1 invalidated after ----
__device__ __forceinline__ void grid_sync(int* cnt, int target) {
    __syncthreads();                       // compiler emits vmcnt(0): this block's stores done
    if (threadIdx.x == 0) {
        __threadfence();                   // release to device scope
        __hip_atomic_fetch_add(cnt, 1, __ATOMIC_RELEASE, __HIP_MEMORY_SCOPE_AGENT);
        while (__hip_atomic_load(cnt, __ATOMIC_RELAXED, __HIP_MEMORY_SCOPE_AGENT) < target)
            __builtin_amdgcn_s_sleep(2);
    }
    __syncthreads();
    __threadfence();                       // acquire: invalidate L1 (stale lines from pre-barrier)
}

// ---- one adj row -> compacted ELL indices (values held in regs, one HBM pass) ----
__device__ __forceinline__ void build_row(const float* __restrict__ adj, int* __restrict__ ell,
                                          int* __restrict__ deg, int row, float* smem) {
    int* jls = (int*)smem;                 // [ELLW]
    int* wtot = jls + ELLW;                // [4]
    int t = threadIdx.x, lane = t & 63, wid = t >> 6;
    const float4* a4 = (const float4*)(adj + (size_t)row * NN);
    float4 v[8];
    int c = 0;
    #pragma unroll
    for (int it = 0; it < 8; ++it) {
        v[it] = a4[it * 256 + t];
        c += (v[it].x > 0.f) + (v[it].y > 0.f) + (v[it].z > 0.f) + (v[it].w > 0.f);
    }
    int s = c;                             // wave inclusive scan
    #pragma unroll
    for (int o = 1; o < 64; o <<= 1) { int u = __shfl_up(s, o); if (lane >= o) s += u; }
    if (lane == 63) wtot[wid] = s;
    __syncthreads();
    int offs = 0, total = 0;
    #pragma unroll
    for (int w2 = 0; w2 < 4; ++w2) { int tw = wtot[w2]; total += tw; if (w2 < wid) offs += tw; }
    int pos = offs + s - c;                // exclusive prefix, deterministic order
    #pragma unroll
    for (int it = 0; it < 8; ++it) {
        int j0 = (it * 256 + t) * 4;
        if (v[it].x > 0.f && pos < ELLW) { jls[pos] = j0;     ++pos; }
        if (v[it].y > 0.f && pos < ELLW) { jls[pos] = j0 + 1; ++pos; }
        if (v[it].z > 0.f && pos < ELLW) { jls[pos] = j0 + 2; ++pos; }
        if (v[it].w > 0.f && pos < ELLW) { jls[pos] = j0 + 3; ++pos; }
    }
    __syncthreads();
    int tot = total < ELLW ? total : ELLW;
    int* er = ell + (size_t)row * ELLW;
    for (int k = t; k < tot; k += 256) er[k] = jls[k];       // coalesced
    if (t == 0) deg[row] = tot;
    __syncthreads();                       // protect smem reuse (next row / next phase)
}

// ---- 8-row tile: Y = act(X) @ W, fused attention scores ----
template<int K, bool RELU>
__device__ __forceinline__ void gemm_tile(const float* __restrict__ X, const float* __restrict__ W,
                                          const float* __restrict__ asrc, const float* __restrict__ adst,
                                          float* __restrict__ Y, float* __restrict__ ssrc,
                                          float* __restrict__ sdst, int row0, float* smem) {
    float* Xl = smem;                      // [8*K]
    float* pS = smem + 8 * K;              // [16]
    float* pD = pS + 16;                   // [16]
    int t = threadIdx.x;
    for (int i = t; i < 8 * K; i += 256) {
        float v = X[(size_t)row0 * K + i]; // 8 contiguous rows
        Xl[i] = RELU ? fmaxf(v, 0.f) : v;
    }
    __syncthreads();
    int c = t & 127, rh = t >> 7, lane = t & 63, w = t >> 6, half = w & 1;
    float acc[4] = {0.f, 0.f, 0.f, 0.f};
    for (int k = 0; k < K; ++k) {
        float wv = W[k * HID + c];         // coalesced, L1/L2-resident
        #pragma unroll
        for (int r = 0; r < 4; ++r)
            acc[r] += Xl[(rh * 4 + r) * K + k] * wv;   // LDS broadcast (uniform addr per wave)
    }
    float as = asrc[c], ad = adst[c];
    #pragma unroll
    for (int r = 0; r < 4; ++r) {
        int row = rh * 4 + r;
        Y[(size_t)(row0 + row) * HID + c] = acc[r];
        float ps = acc[r] * as, pd = acc[r] * ad;
        #pragma unroll
        for (int o = 32; o; o >>= 1) { ps += __shfl_xor(ps, o); pd += __shfl_xor(pd, o); }
        if (lane == 0) { pS[half * 8 + row] = ps; pD[half * 8 + row] = pd; }
    }
    __syncthreads();
    if (t < 8) { ssrc[row0 + t] = pS[t] + pS[8 + t]; sdst[row0 + t] = pD[t] + pD[8 + t]; }
    __syncthreads();
}

// ---- one row of sparse masked softmax + aggregation (one wave) ----
__device__ __forceinline__ void agg_row(const float* __restrict__ h, const float* __restrict__ ssrc,
                                        const float* __restrict__ sdst, const int* __restrict__ ell,
                                        const int* __restrict__ deg, float* __restrict__ out,
                                        int row, int wid, int l, float* smem) {
    float* wl = smem + wid * ELLW;                 // per-wave region
    int* jl = (int*)(smem + 4 * ELLW) + wid * ELLW;
    int d = deg[row];
    float si = ssrc[row];
    const int* er = ell + (size_t)row * ELLW;
    float m = -1e30f;
    for (int k = l; k < d; k += 64) {
        int j = er[k];
        float e = si + sdst[j];
        e = e > 0.f ? e : NEGSLOPE * e;
        jl[k] = j; wl[k] = e;
        m = fmaxf(m, e);
    }
    #pragma unroll
    for (int o = 32; o; o >>= 1) m = fmaxf(m, __shfl_xor(m, o));
    float s = 0.f;
    for (int k = l; k < d; k += 64) {
        float w = __expf(wl[k] - m);
        wl[k] = w;
        s += w;
    }
    #pragma unroll
    for (int o = 32; o; o >>= 1) s += __shfl_xor(s, o);
    float inv = 1.f / s;
    // gather-sum, lane owns dims 2l,2l+1; 4x unroll for memory-level parallelism
    float a0 = 0.f, a1 = 0.f;
    const float* h2l = h + 2 * l;
    int k = 0;
    for (; k + 4 <= d; k += 4) {
        int j0 = jl[k], j1 = jl[k + 1], j2 = jl[k + 2], j3 = jl[k + 3];
        float w0 = wl[k], w1 = wl[k + 1], w2 = wl[k + 2], w3 = wl[k + 3];
        float2 v0 = *(const float2*)(h2l + (size_t)j0 * HID);
        float2 v1 = *(const float2*)(h2l + (size_t)j1 * HID);
        float2 v2 = *(const float2*)(h2l + (size_t)j2 * HID);
        float2 v3 = *(const float2*)(h2l + (size_t)j3 * HID);
        a0 += w0 * v0.x; a1 += w0 * v0.y;
        a0 += w1 * v1.x; a1 += w1 * v1.y;
        a0 += w2 * v2.x; a1 += w2 * v2.y;
        a0 += w3 * v3.x; a1 += w3 * v3.y;
    }
    for (; k < d; ++k) {
        int j = jl[k];
        float w = wl[k];
        float2 v = *(const float2*)(h2l + (size_t)j * HID);
        a0 += w * v.x; a1 += w * v.y;
    }
    float2 o2; o2.x = a0 * inv; o2.y = a1 * inv;
    *(float2*)(out + (size_t)row * HID + 2 * l) = o2;
}

__global__ void k_init(int* cnt) { if (threadIdx.x == 0) *cnt = 0; }

__global__ __launch_bounds__(256, 4) void k_mega(
    const float* __restrict__ x, const float* __restrict__ adj, const int* __restrict__ batch,
    const float* __restrict__ W0, const float* __restrict__ a0s, const float* __restrict__ a0d,
    const float* __restrict__ W1, const float* __restrict__ a1s, const float* __restrict__ a1d,
    const float* __restrict__ W2, const float* __restrict__ a2s, const float* __restrict__ a2d,
    const float* __restrict__ fcw, const float* __restrict__ fcb, float* __restrict__ out,
    int* ell, int* deg, float* hA, float* hB,
    float* ssrc, float* sdst, float* Wr1, float* Wr2, int* cnt) {
    __shared__ float smem[1760];           // 7040 B union: gemm(4K+128B) | agg(6K) | ell(784B)
    int b = blockIdx.x, t = threadIdx.x;
    int wid = t >> 6, l = t & 63;

    // ---- P0: wreduce + gemm0/scores0 + ELL build (all independent; ELL is the HBM floor) ----
    if (b < 128) {                         // W1,W2 [1024,128] -> Wr [128,128]
        const float* W = (b < 64) ? W1 : W2;
        float* Wr = (b < 64) ? Wr1 : Wr2;
        int i = (b & 63) * 256 + t;
        int k = i >> 7, c2 = i & 127;
        float s = 0.f;
        #pragma unroll
        for (int h2 = 0; h2 < HEADS; ++h2) s += W[(size_t)(h2 * HID + k) * HID + c2];
        Wr[i] = s;
    }
    gemm_tile<ATOMF, false>(x, W0, a0s, a0d, hA, ssrc, sdst, b * 8, smem);
    #pragma unroll 1
    for (int i = 0; i < 8; ++i) build_row(adj, ell, deg, b + i * NB, smem);
    grid_sync(cnt, NB);

    // ---- P1: agg layer 0 ----
    agg_row(hA, ssrc, sdst, ell, deg, hB, b * 4 + wid, wid, l, smem);
    agg_row(hA, ssrc, sdst, ell, deg, hB, 4096 + b * 4 + wid, wid, l, smem);
    grid_sync(cnt, 2 * NB);

    // ---- P2: gemm1 (tile+relu collapses to relu(h) @ Wr1) ----
    gemm_tile<HID, true>(hB, Wr1, a1s, a1d, hA, ssrc, sdst, b * 8, smem);
    grid_sync(cnt, 3 * NB);

    // ---- P3: agg layer 1 ----
    agg_row(hA, ssrc, sdst, ell, deg, hB, b * 4 + wid, wid, l, smem);
    agg_row(hA, ssrc, sdst, ell, deg, hB, 4096 + b * 4 + wid, wid, l, smem);
    grid_sync(cnt, 4 * NB);

    // ---- P4: gemm2 ----
    gemm_tile<HID, true>(hB, Wr2, a2s, a2d, hA, ssrc, sdst, b * 8, smem);
    grid_sync(cnt, 5 * NB);

    // ---- P5: agg layer 2 ----
    agg_row(hA, ssrc, sdst, ell, deg, hB, b * 4 + wid, wid, l, smem);
    agg_row(hA, ssrc, sdst, ell, deg, hB, 4096 + b * 4 + wid, wid, l, smem);
    grid_sync(cnt, 6 * NB);

    // ---- P6: pool + fc, one graph per wave, no atomics (deterministic) ----
    if (b < 64) {
        int g = b * 4 + wid;
        int lo = 0, hi = NN;
        while (lo < hi) { int mid = (lo + hi) >> 1; if (batch[mid] < g) lo = mid + 1; else hi = mid; }
        int e0 = lo;
        hi = NN;
        while (lo < hi) { int mid = (lo + hi) >> 1; if (batch[mid] <= g) lo = mid + 1; else hi = mid; }
        int e1 = lo;
        float sum = 0.f;
        for (int r = e0; r < e1; ++r) {
            const float* hr = hB + (size_t)r * HID;
            float p = hr[l] * fcw[l] + hr[l + 64] * fcw[l + 64];
            #pragma unroll
            for (int o = 32; o; o >>= 1) p += __shfl_xor(p, o);
            sum += p;
        }
        if (l == 0) out[g] = sum / fmaxf((float)(e1 - e0), 1.f) + fcb[0];
    }
}

extern "C" void kernel_launch(void* const* d_in, const int* in_sizes, int n_in,
                              void* d_out, int out_size, void* d_ws, size_t ws_size,
                              hipStream_t stream) {
    const float* x    = (const float*)d_in[0];
    const float* adj  = (const float*)d_in[1];
    const int*   batch= (const int*)  d_in[2];
    const float* W0   = (const float*)d_in[3];
    const float* a0s  = (const float*)d_in[4];
    const float* a0d  = (const float*)d_in[5];
    const float* W1   = (const float*)d_in[6];
    const float* a1s  = (const float*)d_in[7];
    const float* a1d  = (const float*)d_in[8];
    const float* W2   = (const float*)d_in[9];
    const float* a2s  = (const float*)d_in[10];
    const float* a2d  = (const float*)d_in[11];
    const float* fcw  = (const float*)d_in[12];
    const float* fcb  = (const float*)d_in[13];
    float* out = (float*)d_out;

    char* ws = (char*)d_ws;
    size_t off = 0;
    auto alloc = [&](size_t bytes) {
        char* p = ws + off;
        off = (off + bytes + 255) & ~255UL;
        return p;
    };
    int*   ell  = (int*)  alloc((size_t)NN * ELLW * 4);   // 6.3 MB
    int*   deg  = (int*)  alloc((size_t)NN * 4);
    float* hA   = (float*)alloc((size_t)NN * HID * 4);    // 4 MB
    float* hB   = (float*)alloc((size_t)NN * HID * 4);    // 4 MB
    float* ssrc = (float*)alloc((size_t)NN * 4);
    float* sdst = (float*)alloc((size_t)NN * 4);
    float* Wr1  = (float*)alloc((size_t)HID * HID * 4);
    float* Wr2  = (float*)alloc((size_t)HID * HID * 4);
    int*   cnt  = (int*)  alloc(256);
    (void)ws_size; (void)in_sizes; (void)n_in; (void)out_size;

    k_init<<<1, 64, 0, stream>>>(cnt);
    k_mega<<<NB, 256, 0, stream>>>(x, adj, batch, W0, a0s, a0d, W1, a1s, a1d,
                                   W2, a2s, a2d, fcw, fcb, out,
                                   ell, deg, hA, hB, ssrc, sdst, Wr1, Wr2, cnt);
}

// Round 4
// 201.883 us; speedup vs baseline: 7.0310x; 7.0310x over previous
//
#include <hip/hip_runtime.h>
#include <cstdint>
#include <cstddef>

#define NN 8192
#define ATOMF 64
#define HID 128
#define HEADS 8
#define NG 256
#define ELLW 192
#define NEGSLOPE 0.2f

// ---- build ELL edge list from dense adj (one HBM pass, values held in regs) ----
// R1 version, verbatim (measured-good in the 198us run).
__global__ __launch_bounds__(256) void k_build_ell(const float* __restrict__ adj,
                                                   int* __restrict__ ell,
                                                   int* __restrict__ deg) {
    int row = blockIdx.x;
    int t = threadIdx.x;
    const float4* a4 = (const float4*)(adj + (size_t)row * NN);
    float4 v[8];
    int c = 0;
    #pragma unroll
    for (int it = 0; it < 8; ++it) {
        v[it] = a4[it * 256 + t];
        c += (v[it].x > 0.f) + (v[it].y > 0.f) + (v[it].z > 0.f) + (v[it].w > 0.f);
    }
    __shared__ int cnt[256];
    cnt[t] = c;
    __syncthreads();
    for (int off = 1; off < 256; off <<= 1) {
        int x = (t >= off) ? cnt[t - off] : 0;
        __syncthreads();
        cnt[t] += x;
        __syncthreads();
    }
    int pos = cnt[t] - c;          // exclusive prefix (deterministic order)
    int total = cnt[255];
    int* er = ell + (size_t)row * ELLW;
    #pragma unroll
    for (int it = 0; it < 8; ++it) {
        int j0 = (it * 256 + t) * 4;
        if (v[it].x > 0.f && pos < ELLW) { er[pos] = j0;     ++pos; }
        if (v[it].y > 0.f && pos < ELLW) { er[pos] = j0 + 1; ++pos; }
        if (v[it].z > 0.f && pos < ELLW) { er[pos] = j0 + 2; ++pos; }
        if (v[it].w > 0.f && pos < ELLW) { er[pos] = j0 + 3; ++pos; }
    }
    if (t == 0) deg[row] = total < ELLW ? total : ELLW;
}

// ---- reduce W1,W2 [1024,128] over their 8 row-blocks -> Wr [128,128] (fused) ----
__global__ __launch_bounds__(256) void k_wreduce(const float* __restrict__ W1,
                                                 const float* __restrict__ W2,
                                                 float* __restrict__ Wr1,
                                                 float* __restrict__ Wr2) {
    int b = blockIdx.x;
    const float* W = (b < 64) ? W1 : W2;
    float* Wr = (b < 64) ? Wr1 : Wr2;
    int i = (b & 63) * 256 + threadIdx.x;
    int k = i >> 7, c = i & 127;
    float s = 0.f;
    #pragma unroll
    for (int h = 0; h < HEADS; ++h)
        s += W[(size_t)(h * HID + k) * HID + c];
    Wr[i] = s;
}

// ---- Y[N,128] = act(X[N,K]) @ W[K,128] — R1 version, verbatim ----
template<int K, bool RELU>
__global__ __launch_bounds__(256) void k_gemm(const float* __restrict__ X,
                                              const float* __restrict__ W,
                                              float* __restrict__ Y) {
    __shared__ float Xl[32 * K];
    int t = threadIdx.x;
    int row0 = blockIdx.x * 32;
    for (int i = t; i < 32 * K; i += 256) {
        int r = i / K, k = i % K;
        float x = X[(size_t)(row0 + r) * K + k];
        Xl[i] = RELU ? fmaxf(x, 0.f) : x;
    }
    __syncthreads();
    int c = t & 127;
    int rh = t >> 7;
    float acc[16];
    #pragma unroll
    for (int m = 0; m < 16; ++m) acc[m] = 0.f;
    for (int k = 0; k < K; ++k) {
        float w = W[k * HID + c];
        #pragma unroll
        for (int m = 0; m < 16; ++m)
            acc[m] += Xl[(rh * 16 + m) * K + k] * w;
    }
    #pragma unroll
    for (int m = 0; m < 16; ++m)
        Y[(size_t)(row0 + rh * 16 + m) * HID + c] = acc[m];
}

// ---- per-row attention scores — R1 version, verbatim ----
__global__ __launch_bounds__(256) void k_scores(const float* __restrict__ h,
                                                const float* __restrict__ asrc,
                                                const float* __restrict__ adst,
                                                float* __restrict__ ssrc,
                                                float* __restrict__ sdst) {
    int wid = threadIdx.x >> 6;
    int lane = threadIdx.x & 63;
    int row = blockIdx.x * 4 + wid;
    const float* hr = h + (size_t)row * HID;
    float h0 = hr[lane], h1 = hr[lane + 64];
    float ps = h0 * asrc[lane] + h1 * asrc[lane + 64];
    float pd = h0 * adst[lane] + h1 * adst[lane + 64];
    #pragma unroll
    for (int o = 32; o; o >>= 1) {
        ps += __shfl_xor(ps, o);
        pd += __shfl_xor(pd, o);
    }
    if (lane == 0) { ssrc[row] = ps; sdst[row] = pd; }
}

// ---- sparse masked softmax + aggregation. 4 rows/block, wave-per-row, no barriers.
// Phase C manually unrolled 8x: 8 independent 512B loads in flight per wave (MLP).
__global__ __launch_bounds__(256, 6) void k_agg(const float* __restrict__ h,
                                                const float* __restrict__ ssrc,
                                                const float* __restrict__ sdst,
                                                const int* __restrict__ ell,
                                                const int* __restrict__ deg,
                                                float* __restrict__ out) {
    __shared__ float wls[4][ELLW];
    __shared__ int jls[4][ELLW];
    int wid = threadIdx.x >> 6;
    int l = threadIdx.x & 63;
    int row = blockIdx.x * 4 + wid;
    float* wl = wls[wid];
    int* jl = jls[wid];
    int d = deg[row];
    float si = ssrc[row];
    const int* er = ell + (size_t)row * ELLW;
    // phase A: e = leakyrelu(src_i + dst_j), running max (wave-local, no barriers)
    float m = -1e30f;
    for (int k = l; k < d; k += 64) {
        int j = er[k];
        float e = si + sdst[j];
        e = e > 0.f ? e : NEGSLOPE * e;
        jl[k] = j; wl[k] = e;
        m = fmaxf(m, e);
    }
    #pragma unroll
    for (int o = 32; o; o >>= 1) m = fmaxf(m, __shfl_xor(m, o));
    // phase B: w = exp(e - m), denom
    float s = 0.f;
    for (int k = l; k < d; k += 64) {
        float w = __expf(wl[k] - m);
        wl[k] = w;
        s += w;
    }
    #pragma unroll
    for (int o = 32; o; o >>= 1) s += __shfl_xor(s, o);
    float inv = 1.f / s;
    // phase C: weighted gather-sum; lane owns dims 2l, 2l+1
    float a0 = 0.f, a1 = 0.f;
    const float* h2l = h + 2 * l;
    int k = 0;
    for (; k + 8 <= d; k += 8) {
        int j0 = jl[k],     j1 = jl[k + 1], j2 = jl[k + 2], j3 = jl[k + 3];
        int j4 = jl[k + 4], j5 = jl[k + 5], j6 = jl[k + 6], j7 = jl[k + 7];
        float w0 = wl[k],     w1 = wl[k + 1], w2 = wl[k + 2], w3 = wl[k + 3];
        float w4 = wl[k + 4], w5 = wl[k + 5], w6 = wl[k + 6], w7 = wl[k + 7];
        float2 v0 = *(const float2*)(h2l + (size_t)j0 * HID);
        float2 v1 = *(const float2*)(h2l + (size_t)j1 * HID);
        float2 v2 = *(const float2*)(h2l + (size_t)j2 * HID);
        float2 v3 = *(const float2*)(h2l + (size_t)j3 * HID);
        float2 v4 = *(const float2*)(h2l + (size_t)j4 * HID);
        float2 v5 = *(const float2*)(h2l + (size_t)j5 * HID);
        float2 v6 = *(const float2*)(h2l + (size_t)j6 * HID);
        float2 v7 = *(const float2*)(h2l + (size_t)j7 * HID);
        a0 += w0 * v0.x; a1 += w0 * v0.y;
        a0 += w1 * v1.x; a1 += w1 * v1.y;
        a0 += w2 * v2.x; a1 += w2 * v2.y;
        a0 += w3 * v3.x; a1 += w3 * v3.y;
        a0 += w4 * v4.x; a1 += w4 * v4.y;
        a0 += w5 * v5.x; a1 += w5 * v5.y;
        a0 += w6 * v6.x; a1 += w6 * v6.y;
        a0 += w7 * v7.x; a1 += w7 * v7.y;
    }
    for (; k < d; ++k) {
        int j = jl[k];
        float w = wl[k];
        float2 v = *(const float2*)(h2l + (size_t)j * HID);
        a0 += w * v.x; a1 += w * v.y;
    }
    float2 o2; o2.x = a0 * inv; o2.y = a1 * inv;
    *(float2*)(out + (size_t)row * HID + 2 * l) = o2;
}

// ---- pool + fc: one graph per wave (batch sorted), no atomics, deterministic ----
__global__ __launch_bounds__(256) void k_poolfc(const float* __restrict__ h,
                                                const int* __restrict__ batch,
                                                const float* __restrict__ fcw,
                                                const float* __restrict__ fcb,
                                                float* __restrict__ out) {
    int wid = threadIdx.x >> 6, l = threadIdx.x & 63;
    int g = blockIdx.x * 4 + wid;
    int lo = 0, hi = NN;
    while (lo < hi) { int mid = (lo + hi) >> 1; if (batch[mid] < g) lo = mid + 1; else hi = mid; }
    int e0 = lo;
    hi = NN;
    while (lo < hi) { int mid = (lo + hi) >> 1; if (batch[mid] <= g) lo = mid + 1; else hi = mid; }
    int e1 = lo;
    float sum = 0.f;
    for (int r = e0; r < e1; ++r) {
        const float* hr = h + (size_t)r * HID;
        sum += hr[l] * fcw[l] + hr[l + 64] * fcw[l + 64];
    }
    #pragma unroll
    for (int o = 32; o; o >>= 1) sum += __shfl_xor(sum, o);
    if (l == 0) out[g] = sum / fmaxf((float)(e1 - e0), 1.f) + fcb[0];
}

extern "C" void kernel_launch(void* const* d_in, const int* in_sizes, int n_in,
                              void* d_out, int out_size, void* d_ws, size_t ws_size,
                              hipStream_t stream) {
    const float* x    = (const float*)d_in[0];
    const float* adj  = (const float*)d_in[1];
    const int*   batch= (const int*)  d_in[2];
    const float* W0   = (const float*)d_in[3];
    const float* a0s  = (const float*)d_in[4];
    const float* a0d  = (const float*)d_in[5];
    const float* W1   = (const float*)d_in[6];
    const float* a1s  = (const float*)d_in[7];
    const float* a1d  = (const float*)d_in[8];
    const float* W2   = (const float*)d_in[9];
    const float* a2s  = (const float*)d_in[10];
    const float* a2d  = (const float*)d_in[11];
    const float* fcw  = (const float*)d_in[12];
    const float* fcb  = (const float*)d_in[13];
    float* out = (float*)d_out;

    char* ws = (char*)d_ws;
    size_t off = 0;
    auto alloc = [&](size_t bytes) {
        char* p = ws + off;
        off = (off + bytes + 255) & ~255UL;
        return p;
    };
    int*   ell  = (int*)  alloc((size_t)NN * ELLW * 4);   // 6.3 MB
    int*   deg  = (int*)  alloc((size_t)NN * 4);
    float* hA   = (float*)alloc((size_t)NN * HID * 4);    // 4 MB
    float* hB   = (float*)alloc((size_t)NN * HID * 4);    // 4 MB
    float* ssrc = (float*)alloc((size_t)NN * 4);
    float* sdst = (float*)alloc((size_t)NN * 4);
    float* Wr1  = (float*)alloc((size_t)HID * HID * 4);
    float* Wr2  = (float*)alloc((size_t)HID * HID * 4);
    (void)ws_size; (void)in_sizes; (void)n_in; (void)out_size;

    k_build_ell<<<NN, 256, 0, stream>>>(adj, ell, deg);
    k_wreduce<<<128, 256, 0, stream>>>(W1, W2, Wr1, Wr2);

    // layer 0
    k_gemm<ATOMF, false><<<NN / 32, 256, 0, stream>>>(x, W0, hA);
    k_scores<<<NN / 4, 256, 0, stream>>>(hA, a0s, a0d, ssrc, sdst);
    k_agg<<<NN / 4, 256, 0, stream>>>(hA, ssrc, sdst, ell, deg, hB);
    // layer 1 (tile+relu collapses to relu(h) @ Wr1)
    k_gemm<HID, true><<<NN / 32, 256, 0, stream>>>(hB, Wr1, hA);
    k_scores<<<NN / 4, 256, 0, stream>>>(hA, a1s, a1d, ssrc, sdst);
    k_agg<<<NN / 4, 256, 0, stream>>>(hA, ssrc, sdst, ell, deg, hB);
    // layer 2
    k_gemm<HID, true><<<NN / 32, 256, 0, stream>>>(hB, Wr2, hA);
    k_scores<<<NN / 4, 256, 0, stream>>>(hA, a2s, a2d, ssrc, sdst);
    k_agg<<<NN / 4, 256, 0, stream>>>(hA, ssrc, sdst, ell, deg, hB);

    // fused global mean pool + fc
    k_poolfc<<<NG / 4, 256, 0, stream>>>(hB, batch, fcw, fcb, out);
}